// Round 6
// baseline (1247.314 us; speedup 1.0000x reference)
//
#include <hip/hip_runtime.h>

// Actor_attf_single — MI355X (gfx950)
// R6: TLP unlock. Evidence: R3 (1 row/thr, 4096 waves = 4/SIMD, FETCH=101MB)
// 361us; R5 (2 rows/thr, 2048 waves = 2/SIMD, FETCH=4x input from L2 thrash)
// 457us. Kernel is latency-bound and grid-TLP-capped, NOT issue-bound.
// This round: 2 THREADS PER ROW (8192 waves = 8/SIMD available):
//   - even/odd lane pair shares one row; each computes half the attention
//     agents with a private online-softmax state; states merged with
//     __shfl_xor(.,1) (exact same term set, just re-associated)
//   - action head split by output halves across the lane pair, shuffle-merged
//   - weights via 22 direct uniform pointers (s_load, proven in R3)
//   - lean scalar fp32 registers (R4 spill lesson); __launch_bounds__(256,4)

#define LN_EPS 1e-5f

struct Weights {
  const float* __restrict__ en_W1; const float* __restrict__ en_b1;
  const float* __restrict__ en_W2; const float* __restrict__ en_b2;
  const float* __restrict__ oa_W1; const float* __restrict__ oa_b1;
  const float* __restrict__ oa_W2; const float* __restrict__ oa_b2;
  const float* __restrict__ go_W1; const float* __restrict__ go_b1;
  const float* __restrict__ go_W2; const float* __restrict__ go_b2;
  const float* __restrict__ oa_g;  const float* __restrict__ oa_b;
  const float* __restrict__ go_g;  const float* __restrict__ go_b;
  const float* __restrict__ a_W1;  const float* __restrict__ a_b1;
  const float* __restrict__ a_W2;  const float* __restrict__ a_b2;
  const float* __restrict__ a_W3;  const float* __restrict__ a_b3;
};

__device__ __forceinline__ float2 ld2(const float* __restrict__ p) {
  return *reinterpret_cast<const float2*>(p);
}

__global__ __launch_bounds__(256, 4)
void actor_fwd(const float* __restrict__ s_input, Weights W,
               float* __restrict__ out, int bsz) {
  const int t   = blockIdx.x * 256 + threadIdx.x;
  const int row = t >> 1;
  if (row >= bsz) return;
  const int half = t & 1;                       // lane parity; partner = lane^1
  const float* __restrict__ srow = s_input + (size_t)row * 96;

  // -------- self encoder: 4 -> 32 -> 16, relu (duplicated in both halves) ----
  float self_out[16];
  {
    float2 p01 = ld2(srow + 0);
    float2 p23 = ld2(srow + 2);
    float h[32];
#pragma unroll
    for (int j = 0; j < 32; ++j) {
      float v = W.en_b1[j];
      v = fmaf(p01.x, W.en_W1[ 0 + j], v);
      v = fmaf(p01.y, W.en_W1[32 + j], v);
      v = fmaf(p23.x, W.en_W1[64 + j], v);
      v = fmaf(p23.y, W.en_W1[96 + j], v);
      h[j] = fmaxf(v, 0.f);
    }
#pragma unroll
    for (int d = 0; d < 16; ++d) {
      float v = W.en_b2[d];
#pragma unroll
      for (int j = 0; j < 32; ++j) v = fmaf(h[j], W.en_W2[j*16 + d], v);
      self_out[d] = fmaxf(v, 0.f);
    }
  }

  // ------ other agents: 15 x (4->32->16); even lanes k=0..7, odd k=8..14 ----
  float other_pool[16];
  {
    float m = -3.0e38f, l = 0.f, acc[16];
#pragma unroll
    for (int d = 0; d < 16; ++d) acc[d] = 0.f;
    const int k0 = half * 8;
    const int k1 = half ? 15 : 8;
#pragma unroll 1
    for (int k = k0; k < k1; ++k) {
      float2 a01 = ld2(srow + 4  + 2*k);
      float2 a23 = ld2(srow + 34 + 2*k);
      float h[32];
#pragma unroll
      for (int j = 0; j < 32; ++j) {
        float v = W.oa_b1[j];
        v = fmaf(a01.x, W.oa_W1[ 0 + j], v);
        v = fmaf(a01.y, W.oa_W1[32 + j], v);
        v = fmaf(a23.x, W.oa_W1[64 + j], v);
        v = fmaf(a23.y, W.oa_W1[96 + j], v);
        h[j] = fmaxf(v, 0.f);
      }
      float enc[16];
#pragma unroll
      for (int d = 0; d < 16; ++d) {
        float v = W.oa_b2[d];
#pragma unroll
        for (int j = 0; j < 32; ++j) v = fmaf(h[j], W.oa_W2[j*16 + d], v);
        enc[d] = fmaxf(v, 0.f);
      }
      float s = 0.f;
#pragma unroll
      for (int d = 0; d < 16; ++d) s = fmaf(self_out[d], enc[d], s);
      s *= 0.25f;                               // 1/sqrt(16)
      float mn    = fmaxf(m, s);
      float alpha = __expf(m - mn);             // first iter: exp(-huge)==0
      float w     = __expf(s - mn);
      l = fmaf(l, alpha, w);
#pragma unroll
      for (int d = 0; d < 16; ++d) acc[d] = fmaf(acc[d], alpha, w * enc[d]);
      m = mn;
    }
    // ---- merge the two half-states across the lane pair (both halves >=7) --
    float pm = __shfl_xor(m, 1);
    float pl = __shfl_xor(l, 1);
    float M  = fmaxf(m, pm);
    float ea = __expf(m - M), eb = __expf(pm - M);
    l = l * ea + pl * eb;
#pragma unroll
    for (int d = 0; d < 16; ++d) {
      float pa = __shfl_xor(acc[d], 1);
      acc[d] = acc[d] * ea + pa * eb;
    }
    float inv = 1.f / l;
    float mu = 0.f;
#pragma unroll
    for (int d = 0; d < 16; ++d) { acc[d] *= inv; mu += acc[d]; }
    mu *= (1.f / 16.f);
    float var = 0.f;
#pragma unroll
    for (int d = 0; d < 16; ++d) { float x = acc[d] - mu; var = fmaf(x, x, var); }
    var *= (1.f / 16.f);
    float rstd = rsqrtf(var + LN_EPS);
#pragma unroll
    for (int d = 0; d < 16; ++d)
      other_pool[d] = fmaxf(fmaf((acc[d] - mu) * rstd, W.oa_g[d], W.oa_b[d]), 0.f);
  }

  // ------ food: 16 x (2->32->16); even lanes k=0..7, odd k=8..15 ------
  float food_pool[16];
  {
    float m = -3.0e38f, l = 0.f, acc[16];
#pragma unroll
    for (int d = 0; d < 16; ++d) acc[d] = 0.f;
    const int k0 = half * 8;
    const int k1 = k0 + 8;
#pragma unroll 1
    for (int k = k0; k < k1; ++k) {
      float2 f01 = ld2(srow + 64 + 2*k);
      float h[32];
#pragma unroll
      for (int j = 0; j < 32; ++j) {
        float v = W.go_b1[j];
        v = fmaf(f01.x, W.go_W1[ 0 + j], v);
        v = fmaf(f01.y, W.go_W1[32 + j], v);
        h[j] = fmaxf(v, 0.f);
      }
      float enc[16];
#pragma unroll
      for (int d = 0; d < 16; ++d) {
        float v = W.go_b2[d];
#pragma unroll
        for (int j = 0; j < 32; ++j) v = fmaf(h[j], W.go_W2[j*16 + d], v);
        enc[d] = fmaxf(v, 0.f);
      }
      float s = 0.f;
#pragma unroll
      for (int d = 0; d < 16; ++d) s = fmaf(self_out[d], enc[d], s);
      s *= 0.25f;
      float mn    = fmaxf(m, s);
      float alpha = __expf(m - mn);
      float w     = __expf(s - mn);
      l = fmaf(l, alpha, w);
#pragma unroll
      for (int d = 0; d < 16; ++d) acc[d] = fmaf(acc[d], alpha, w * enc[d]);
      m = mn;
    }
    float pm = __shfl_xor(m, 1);
    float pl = __shfl_xor(l, 1);
    float M  = fmaxf(m, pm);
    float ea = __expf(m - M), eb = __expf(pm - M);
    l = l * ea + pl * eb;
#pragma unroll
    for (int d = 0; d < 16; ++d) {
      float pa = __shfl_xor(acc[d], 1);
      acc[d] = acc[d] * ea + pa * eb;
    }
    float inv = 1.f / l;
    float mu = 0.f;
#pragma unroll
    for (int d = 0; d < 16; ++d) { acc[d] *= inv; mu += acc[d]; }
    mu *= (1.f / 16.f);
    float var = 0.f;
#pragma unroll
    for (int d = 0; d < 16; ++d) { float x = acc[d] - mu; var = fmaf(x, x, var); }
    var *= (1.f / 16.f);
    float rstd = rsqrtf(var + LN_EPS);
#pragma unroll
    for (int d = 0; d < 16; ++d)
      food_pool[d] = fmaxf(fmaf((acc[d] - mu) * rstd, W.go_g[d], W.go_b[d]), 0.f);
  }

  // ------- action head: 48->32->32->2; lane pair splits output halves -------
  // merged order: [self, food, other]. Each lane computes 16 of 32 h1 cols.
  const int jb = half * 16;
  float h1[16];
#pragma unroll
  for (int i = 0; i < 16; ++i) h1[i] = W.a_b1[jb + i];
#pragma unroll
  for (int c = 0; c < 16; ++c) {
    float v = self_out[c];
#pragma unroll
    for (int i = 0; i < 16; ++i) h1[i] = fmaf(v, W.a_W1[c*32 + jb + i], h1[i]);
  }
#pragma unroll
  for (int c = 0; c < 16; ++c) {
    float v = food_pool[c];
#pragma unroll
    for (int i = 0; i < 16; ++i) h1[i] = fmaf(v, W.a_W1[(16 + c)*32 + jb + i], h1[i]);
  }
#pragma unroll
  for (int c = 0; c < 16; ++c) {
    float v = other_pool[c];
#pragma unroll
    for (int i = 0; i < 16; ++i) h1[i] = fmaf(v, W.a_W1[(32 + c)*32 + jb + i], h1[i]);
  }
#pragma unroll
  for (int i = 0; i < 16; ++i)
    h1[i] = fmaxf(h1[i], 0.f) + 0.01f * fminf(h1[i], 0.f);      // leaky_relu

  // merge h1 halves -> full h1f[32] in both lanes
  float h1f[32];
#pragma unroll
  for (int i = 0; i < 16; ++i) {
    float p = __shfl_xor(h1[i], 1);
    h1f[i]      = half ? p : h1[i];
    h1f[16 + i] = half ? h1[i] : p;
  }

  float h2[16];
#pragma unroll
  for (int i = 0; i < 16; ++i) h2[i] = W.a_b2[jb + i];
#pragma unroll
  for (int c = 0; c < 32; ++c) {
#pragma unroll
    for (int i = 0; i < 16; ++i) h2[i] = fmaf(h1f[c], W.a_W2[c*32 + jb + i], h2[i]);
  }
#pragma unroll
  for (int i = 0; i < 16; ++i)
    h2[i] = fmaxf(h2[i], 0.f) + 0.01f * fminf(h2[i], 0.f);

  // merge h2 halves -> full h2f[32] in both lanes
  float h2f[32];
#pragma unroll
  for (int i = 0; i < 16; ++i) {
    float p = __shfl_xor(h2[i], 1);
    h2f[i]      = half ? p : h2[i];
    h2f[16 + i] = half ? h2[i] : p;
  }

  float o0 = W.a_b3[0], o1 = W.a_b3[1];
#pragma unroll
  for (int c = 0; c < 32; ++c) {
    o0 = fmaf(h2f[c], W.a_W3[c*2 + 0], o0);
    o1 = fmaf(h2f[c], W.a_W3[c*2 + 1], o1);
  }
  o0 = tanhf(o0);
  o1 = tanhf(o1);

  if (!half)                                      // even lane stores the pair
    reinterpret_cast<float2*>(out)[row] = make_float2(o0, o1);
}

extern "C" void kernel_launch(void* const* d_in, const int* in_sizes, int n_in,
                              void* d_out, int out_size, void* d_ws, size_t ws_size,
                              hipStream_t stream) {
  const float* s_input = (const float*)d_in[0];
  Weights W;
  W.en_W1 = (const float*)d_in[1];  W.en_b1 = (const float*)d_in[2];
  W.en_W2 = (const float*)d_in[3];  W.en_b2 = (const float*)d_in[4];
  W.oa_W1 = (const float*)d_in[5];  W.oa_b1 = (const float*)d_in[6];
  W.oa_W2 = (const float*)d_in[7];  W.oa_b2 = (const float*)d_in[8];
  W.go_W1 = (const float*)d_in[9];  W.go_b1 = (const float*)d_in[10];
  W.go_W2 = (const float*)d_in[11]; W.go_b2 = (const float*)d_in[12];
  W.oa_g  = (const float*)d_in[13]; W.oa_b  = (const float*)d_in[14];
  W.go_g  = (const float*)d_in[15]; W.go_b  = (const float*)d_in[16];
  W.a_W1  = (const float*)d_in[17]; W.a_b1  = (const float*)d_in[18];
  W.a_W2  = (const float*)d_in[19]; W.a_b2  = (const float*)d_in[20];
  W.a_W3  = (const float*)d_in[21]; W.a_b3  = (const float*)d_in[22];

  const int bsz = in_sizes[0] / 96;                 // 262144
  const long threads = 2L * bsz;                    // 2 threads per row
  const int blocks = (int)((threads + 255) / 256);  // 2048
  actor_fwd<<<blocks, 256, 0, stream>>>(s_input, W, (float*)d_out, bsz);
}

// Round 7
// 504.233 us; speedup vs baseline: 2.4737x; 2.4737x over previous
//
#include <hip/hip_runtime.h>

// Actor_attf_single — MI355X (gfx950)
// R7: R3's exact structure (1 row/thread, 4096 waves, direct uniform weight
// pointers, proven FETCH=101MB @ 361us) + float2 packing along the OUTPUT
// dim of every MLP stage. Weight pairs are contiguous => s_load_dwordx2 +
// v_pk_fma_f32 (VOP3P packed fp32, 2 FMA/inst). No new arrays, no LDS, no
// cross-row coupling (lessons: R4 spill, R5 L2-thrash, R6 lane-split loss).

#define LN_EPS 1e-5f

struct Weights {
  const float* __restrict__ en_W1; const float* __restrict__ en_b1;
  const float* __restrict__ en_W2; const float* __restrict__ en_b2;
  const float* __restrict__ oa_W1; const float* __restrict__ oa_b1;
  const float* __restrict__ oa_W2; const float* __restrict__ oa_b2;
  const float* __restrict__ go_W1; const float* __restrict__ go_b1;
  const float* __restrict__ go_W2; const float* __restrict__ go_b2;
  const float* __restrict__ oa_g;  const float* __restrict__ oa_b;
  const float* __restrict__ go_g;  const float* __restrict__ go_b;
  const float* __restrict__ a_W1;  const float* __restrict__ a_b1;
  const float* __restrict__ a_W2;  const float* __restrict__ a_b2;
  const float* __restrict__ a_W3;  const float* __restrict__ a_b3;
};

__device__ __forceinline__ float2 ld2(const float* __restrict__ p) {
  return *reinterpret_cast<const float2*>(p);
}
// packed helpers: elementwise on float2 (ISel -> v_pk_*_f32)
__device__ __forceinline__ float2 pkfma(float2 a, float2 b, float2 c) {
  return make_float2(fmaf(a.x, b.x, c.x), fmaf(a.y, b.y, c.y));
}
__device__ __forceinline__ float2 pkfma_s(float s, float2 b, float2 c) {
  return make_float2(fmaf(s, b.x, c.x), fmaf(s, b.y, c.y));
}
__device__ __forceinline__ float2 pkmax0(float2 a) {
  return make_float2(fmaxf(a.x, 0.f), fmaxf(a.y, 0.f));
}

__global__ __launch_bounds__(256)
void actor_fwd(const float* __restrict__ s_input, Weights W,
               float* __restrict__ out, int bsz) {
  const int row = blockIdx.x * blockDim.x + threadIdx.x;
  if (row >= bsz) return;
  const float* __restrict__ srow = s_input + (size_t)row * 96;

  // ---------------- self encoder: 4 -> 32 -> 16, relu ----------------
  float2 self2[8];
  {
    float2 p01 = ld2(srow + 0);
    float2 p23 = ld2(srow + 2);
    float2 h2[16];
#pragma unroll
    for (int i = 0; i < 16; ++i) {
      float2 h = ld2(W.en_b1 + 2*i);
      h = pkfma_s(p01.x, ld2(W.en_W1 +  0 + 2*i), h);
      h = pkfma_s(p01.y, ld2(W.en_W1 + 32 + 2*i), h);
      h = pkfma_s(p23.x, ld2(W.en_W1 + 64 + 2*i), h);
      h = pkfma_s(p23.y, ld2(W.en_W1 + 96 + 2*i), h);
      h2[i] = pkmax0(h);
    }
#pragma unroll
    for (int i = 0; i < 8; ++i) self2[i] = ld2(W.en_b2 + 2*i);
#pragma unroll
    for (int j = 0; j < 32; ++j) {
      float hj = (j & 1) ? h2[j >> 1].y : h2[j >> 1].x;
      const float* wr = W.en_W2 + j*16;
#pragma unroll
      for (int i = 0; i < 8; ++i) self2[i] = pkfma_s(hj, ld2(wr + 2*i), self2[i]);
    }
#pragma unroll
    for (int i = 0; i < 8; ++i) self2[i] = pkmax0(self2[i]);
  }

  // ------- other agents: 15 x (4 -> 32 -> 16) + online-softmax attend -------
  float2 otherP[8];
  {
    float m = -3.0e38f, l = 0.f;
    float2 acc[8];
#pragma unroll
    for (int i = 0; i < 8; ++i) acc[i] = make_float2(0.f, 0.f);
#pragma unroll 1
    for (int k = 0; k < 15; ++k) {
      float2 a01 = ld2(srow + 4  + 2*k);
      float2 a23 = ld2(srow + 34 + 2*k);
      float2 h2[16];
#pragma unroll
      for (int i = 0; i < 16; ++i) {
        float2 h = ld2(W.oa_b1 + 2*i);
        h = pkfma_s(a01.x, ld2(W.oa_W1 +  0 + 2*i), h);
        h = pkfma_s(a01.y, ld2(W.oa_W1 + 32 + 2*i), h);
        h = pkfma_s(a23.x, ld2(W.oa_W1 + 64 + 2*i), h);
        h = pkfma_s(a23.y, ld2(W.oa_W1 + 96 + 2*i), h);
        h2[i] = pkmax0(h);
      }
      float2 enc[8];
#pragma unroll
      for (int i = 0; i < 8; ++i) enc[i] = ld2(W.oa_b2 + 2*i);
#pragma unroll
      for (int j = 0; j < 32; ++j) {
        float hj = (j & 1) ? h2[j >> 1].y : h2[j >> 1].x;
        const float* wr = W.oa_W2 + j*16;
#pragma unroll
        for (int i = 0; i < 8; ++i) enc[i] = pkfma_s(hj, ld2(wr + 2*i), enc[i]);
      }
      float2 dot = make_float2(0.f, 0.f);
#pragma unroll
      for (int i = 0; i < 8; ++i) {
        enc[i] = pkmax0(enc[i]);
        dot = pkfma(self2[i], enc[i], dot);
      }
      float s = (dot.x + dot.y) * 0.25f;        // 1/sqrt(16)
      float mn    = fmaxf(m, s);
      float alpha = __expf(m - mn);             // first iter: exp(-huge)==0
      float w     = __expf(s - mn);
      l = fmaf(l, alpha, w);
#pragma unroll
      for (int i = 0; i < 8; ++i) {
        float2 we = make_float2(w * enc[i].x, w * enc[i].y);   // pk_mul
        acc[i] = pkfma_s(alpha, acc[i], we);                   // pk_fma
      }
      m = mn;
    }
    float inv = 1.f / l;
    float mu = 0.f;
#pragma unroll
    for (int i = 0; i < 8; ++i) {
      acc[i].x *= inv; acc[i].y *= inv;
      mu += acc[i].x + acc[i].y;
    }
    mu *= (1.f / 16.f);
    float var = 0.f;
#pragma unroll
    for (int i = 0; i < 8; ++i) {
      float tx = acc[i].x - mu, ty = acc[i].y - mu;
      var = fmaf(tx, tx, var); var = fmaf(ty, ty, var);
    }
    float rstd = rsqrtf(var * (1.f / 16.f) + LN_EPS);
#pragma unroll
    for (int i = 0; i < 8; ++i) {
      float2 g = ld2(W.oa_g + 2*i), b = ld2(W.oa_b + 2*i);
      otherP[i] = pkmax0(make_float2(fmaf((acc[i].x - mu) * rstd, g.x, b.x),
                                     fmaf((acc[i].y - mu) * rstd, g.y, b.y)));
    }
  }

  // ------- food: 16 x (2 -> 32 -> 16) + online-softmax attend -------
  float2 foodP[8];
  {
    float m = -3.0e38f, l = 0.f;
    float2 acc[8];
#pragma unroll
    for (int i = 0; i < 8; ++i) acc[i] = make_float2(0.f, 0.f);
#pragma unroll 1
    for (int k = 0; k < 16; ++k) {
      float2 f01 = ld2(srow + 64 + 2*k);
      float2 h2[16];
#pragma unroll
      for (int i = 0; i < 16; ++i) {
        float2 h = ld2(W.go_b1 + 2*i);
        h = pkfma_s(f01.x, ld2(W.go_W1 +  0 + 2*i), h);
        h = pkfma_s(f01.y, ld2(W.go_W1 + 32 + 2*i), h);
        h2[i] = pkmax0(h);
      }
      float2 enc[8];
#pragma unroll
      for (int i = 0; i < 8; ++i) enc[i] = ld2(W.go_b2 + 2*i);
#pragma unroll
      for (int j = 0; j < 32; ++j) {
        float hj = (j & 1) ? h2[j >> 1].y : h2[j >> 1].x;
        const float* wr = W.go_W2 + j*16;
#pragma unroll
        for (int i = 0; i < 8; ++i) enc[i] = pkfma_s(hj, ld2(wr + 2*i), enc[i]);
      }
      float2 dot = make_float2(0.f, 0.f);
#pragma unroll
      for (int i = 0; i < 8; ++i) {
        enc[i] = pkmax0(enc[i]);
        dot = pkfma(self2[i], enc[i], dot);
      }
      float s = (dot.x + dot.y) * 0.25f;
      float mn    = fmaxf(m, s);
      float alpha = __expf(m - mn);
      float w     = __expf(s - mn);
      l = fmaf(l, alpha, w);
#pragma unroll
      for (int i = 0; i < 8; ++i) {
        float2 we = make_float2(w * enc[i].x, w * enc[i].y);
        acc[i] = pkfma_s(alpha, acc[i], we);
      }
      m = mn;
    }
    float inv = 1.f / l;
    float mu = 0.f;
#pragma unroll
    for (int i = 0; i < 8; ++i) {
      acc[i].x *= inv; acc[i].y *= inv;
      mu += acc[i].x + acc[i].y;
    }
    mu *= (1.f / 16.f);
    float var = 0.f;
#pragma unroll
    for (int i = 0; i < 8; ++i) {
      float tx = acc[i].x - mu, ty = acc[i].y - mu;
      var = fmaf(tx, tx, var); var = fmaf(ty, ty, var);
    }
    float rstd = rsqrtf(var * (1.f / 16.f) + LN_EPS);
#pragma unroll
    for (int i = 0; i < 8; ++i) {
      float2 g = ld2(W.go_g + 2*i), b = ld2(W.go_b + 2*i);
      foodP[i] = pkmax0(make_float2(fmaf((acc[i].x - mu) * rstd, g.x, b.x),
                                    fmaf((acc[i].y - mu) * rstd, g.y, b.y)));
    }
  }

  // ------- action head: 48 -> 32 -> 32 -> 2, leaky_relu(0.01), tanh -------
  // merged order: [self, food, other]
  float2 h1[16];
#pragma unroll
  for (int i = 0; i < 16; ++i) h1[i] = ld2(W.a_b1 + 2*i);
#pragma unroll
  for (int c = 0; c < 16; ++c) {
    float v = (c & 1) ? self2[c >> 1].y : self2[c >> 1].x;
    const float* wr = W.a_W1 + c*32;
#pragma unroll
    for (int i = 0; i < 16; ++i) h1[i] = pkfma_s(v, ld2(wr + 2*i), h1[i]);
  }
#pragma unroll
  for (int c = 0; c < 16; ++c) {
    float v = (c & 1) ? foodP[c >> 1].y : foodP[c >> 1].x;
    const float* wr = W.a_W1 + (16 + c)*32;
#pragma unroll
    for (int i = 0; i < 16; ++i) h1[i] = pkfma_s(v, ld2(wr + 2*i), h1[i]);
  }
#pragma unroll
  for (int c = 0; c < 16; ++c) {
    float v = (c & 1) ? otherP[c >> 1].y : otherP[c >> 1].x;
    const float* wr = W.a_W1 + (32 + c)*32;
#pragma unroll
    for (int i = 0; i < 16; ++i) h1[i] = pkfma_s(v, ld2(wr + 2*i), h1[i]);
  }
  // leaky_relu(v) = max(v, 0.01*v)  (valid: v>=0 -> v; v<0 -> 0.01v > v)
#pragma unroll
  for (int i = 0; i < 16; ++i)
    h1[i] = make_float2(fmaxf(h1[i].x, 0.01f * h1[i].x),
                        fmaxf(h1[i].y, 0.01f * h1[i].y));

  float2 h2a[16];
#pragma unroll
  for (int i = 0; i < 16; ++i) h2a[i] = ld2(W.a_b2 + 2*i);
#pragma unroll
  for (int c = 0; c < 32; ++c) {
    float v = (c & 1) ? h1[c >> 1].y : h1[c >> 1].x;
    const float* wr = W.a_W2 + c*32;
#pragma unroll
    for (int i = 0; i < 16; ++i) h2a[i] = pkfma_s(v, ld2(wr + 2*i), h2a[i]);
  }
#pragma unroll
  for (int i = 0; i < 16; ++i)
    h2a[i] = make_float2(fmaxf(h2a[i].x, 0.01f * h2a[i].x),
                         fmaxf(h2a[i].y, 0.01f * h2a[i].y));

  float2 o2 = ld2(W.a_b3);
#pragma unroll
  for (int c = 0; c < 32; ++c) {
    float v = (c & 1) ? h2a[c >> 1].y : h2a[c >> 1].x;
    o2 = pkfma_s(v, ld2(W.a_W3 + 2*c), o2);
  }
  o2.x = tanhf(o2.x);
  o2.y = tanhf(o2.y);

  reinterpret_cast<float2*>(out)[row] = o2;
}

extern "C" void kernel_launch(void* const* d_in, const int* in_sizes, int n_in,
                              void* d_out, int out_size, void* d_ws, size_t ws_size,
                              hipStream_t stream) {
  const float* s_input = (const float*)d_in[0];
  Weights W;
  W.en_W1 = (const float*)d_in[1];  W.en_b1 = (const float*)d_in[2];
  W.en_W2 = (const float*)d_in[3];  W.en_b2 = (const float*)d_in[4];
  W.oa_W1 = (const float*)d_in[5];  W.oa_b1 = (const float*)d_in[6];
  W.oa_W2 = (const float*)d_in[7];  W.oa_b2 = (const float*)d_in[8];
  W.go_W1 = (const float*)d_in[9];  W.go_b1 = (const float*)d_in[10];
  W.go_W2 = (const float*)d_in[11]; W.go_b2 = (const float*)d_in[12];
  W.oa_g  = (const float*)d_in[13]; W.oa_b  = (const float*)d_in[14];
  W.go_g  = (const float*)d_in[15]; W.go_b  = (const float*)d_in[16];
  W.a_W1  = (const float*)d_in[17]; W.a_b1  = (const float*)d_in[18];
  W.a_W2  = (const float*)d_in[19]; W.a_b2  = (const float*)d_in[20];
  W.a_W3  = (const float*)d_in[21]; W.a_b3  = (const float*)d_in[22];

  const int bsz = in_sizes[0] / 96;          // 262144
  const int blocks = (bsz + 255) / 256;      // 1024
  actor_fwd<<<blocks, 256, 0, stream>>>(s_input, W, (float*)d_out, bsz);
}

// Round 8
// 458.714 us; speedup vs baseline: 2.7192x; 1.0992x over previous
//
#include <hip/hip_runtime.h>

// Actor_attf_single — MI355X (gfx950)
// R8: entity-pair unroll on R3's proven skeleton (1 row/thread, uniform
// weight pointers). Evidence: R3 true issue util only ~23% (4 waves/SIMD x
// 25K inst x 2cyc = 200K cyc vs 866K wall); VALUBusy ~86% is pipeline-depth
// occupancy, not issue slots => stall-bound on per-k-iteration uniform weight
// s_loads (688 words re-fetched per entity, shallow SGPR prefetch batches).
// Fix: process agents (k,k+1) together with W1->W2 fused scalar h:
//   - every s_loaded weight word feeds TWO fmas (per-wave s_load count halves)
//   - two independent acc chains (ILP x2) to cover remaining latency
//   - all loop bounds wave-uniform (R6 lesson: divergent bounds de-scalarize)
//   - numerics bit-identical to R3 (same per-entity op order, sequential folds)
// Register budget: ~100 VGPR < 128 (grid caps occupancy at 4 waves/SIMD, so
// registers are free to spend until 128).

#define LN_EPS 1e-5f

struct Weights {
  const float* __restrict__ en_W1; const float* __restrict__ en_b1;
  const float* __restrict__ en_W2; const float* __restrict__ en_b2;
  const float* __restrict__ oa_W1; const float* __restrict__ oa_b1;
  const float* __restrict__ oa_W2; const float* __restrict__ oa_b2;
  const float* __restrict__ go_W1; const float* __restrict__ go_b1;
  const float* __restrict__ go_W2; const float* __restrict__ go_b2;
  const float* __restrict__ oa_g;  const float* __restrict__ oa_b;
  const float* __restrict__ go_g;  const float* __restrict__ go_b;
  const float* __restrict__ a_W1;  const float* __restrict__ a_b1;
  const float* __restrict__ a_W2;  const float* __restrict__ a_b2;
  const float* __restrict__ a_W3;  const float* __restrict__ a_b3;
};

__device__ __forceinline__ float2 ld2(const float* __restrict__ p) {
  return *reinterpret_cast<const float2*>(p);
}

__global__ __launch_bounds__(256)
void actor_fwd(const float* __restrict__ s_input, Weights W,
               float* __restrict__ out, int bsz) {
  const int row = blockIdx.x * blockDim.x + threadIdx.x;
  if (row >= bsz) return;
  const float* __restrict__ srow = s_input + (size_t)row * 96;

  // ---------------- self encoder: fused 4 -> 32 -> 16, relu ----------------
  float self_out[16];
  {
    float2 p01 = ld2(srow + 0);
    float2 p23 = ld2(srow + 2);
#pragma unroll
    for (int d = 0; d < 16; ++d) self_out[d] = W.en_b2[d];
#pragma unroll
    for (int j = 0; j < 32; ++j) {
      float h = W.en_b1[j];
      h = fmaf(p01.x, W.en_W1[ 0 + j], h);
      h = fmaf(p01.y, W.en_W1[32 + j], h);
      h = fmaf(p23.x, W.en_W1[64 + j], h);
      h = fmaf(p23.y, W.en_W1[96 + j], h);
      h = fmaxf(h, 0.f);
#pragma unroll
      for (int d = 0; d < 16; ++d) self_out[d] = fmaf(h, W.en_W2[j*16 + d], self_out[d]);
    }
#pragma unroll
    for (int d = 0; d < 16; ++d) self_out[d] = fmaxf(self_out[d], 0.f);
  }

  // ------- other agents: 15 x (4->32->16), processed in pairs -------
  float other_pool[16];
  {
    float m = -3.0e38f, l = 0.f, acc[16];
#pragma unroll
    for (int d = 0; d < 16; ++d) acc[d] = 0.f;

#pragma unroll 1
    for (int kp = 0; kp < 14; kp += 2) {
      // entity a = kp, entity b = kp+1; weights shared per j/d
      float2 a01 = ld2(srow + 4  + 2*kp);
      float2 a23 = ld2(srow + 34 + 2*kp);
      float2 b01 = ld2(srow + 4  + 2*kp + 2);
      float2 b23 = ld2(srow + 34 + 2*kp + 2);
      float enc_a[16], enc_b[16];
#pragma unroll
      for (int d = 0; d < 16; ++d) { float b2 = W.oa_b2[d]; enc_a[d] = b2; enc_b[d] = b2; }
#pragma unroll
      for (int j = 0; j < 32; ++j) {
        float w0 = W.oa_W1[ 0 + j], w1 = W.oa_W1[32 + j];
        float w2 = W.oa_W1[64 + j], w3 = W.oa_W1[96 + j];
        float b1 = W.oa_b1[j];
        float ha = fmaf(a01.x, w0, b1); ha = fmaf(a01.y, w1, ha);
        ha = fmaf(a23.x, w2, ha);       ha = fmaf(a23.y, w3, ha);
        ha = fmaxf(ha, 0.f);
        float hb = fmaf(b01.x, w0, b1); hb = fmaf(b01.y, w1, hb);
        hb = fmaf(b23.x, w2, hb);       hb = fmaf(b23.y, w3, hb);
        hb = fmaxf(hb, 0.f);
#pragma unroll
        for (int d = 0; d < 16; ++d) {
          float w = W.oa_W2[j*16 + d];
          enc_a[d] = fmaf(ha, w, enc_a[d]);
          enc_b[d] = fmaf(hb, w, enc_b[d]);
        }
      }
      float sa = 0.f, sb = 0.f;
#pragma unroll
      for (int d = 0; d < 16; ++d) {
        enc_a[d] = fmaxf(enc_a[d], 0.f);
        enc_b[d] = fmaxf(enc_b[d], 0.f);
        sa = fmaf(self_out[d], enc_a[d], sa);
        sb = fmaf(self_out[d], enc_b[d], sb);
      }
      sa *= 0.25f; sb *= 0.25f;                     // 1/sqrt(16)
      // two sequential online-softmax folds (numerically identical to R3)
      {
        float mn = fmaxf(m, sa);
        float alpha = __expf(m - mn), w = __expf(sa - mn);
        l = fmaf(l, alpha, w);
#pragma unroll
        for (int d = 0; d < 16; ++d) acc[d] = fmaf(acc[d], alpha, w * enc_a[d]);
        m = mn;
      }
      {
        float mn = fmaxf(m, sb);
        float alpha = __expf(m - mn), w = __expf(sb - mn);
        l = fmaf(l, alpha, w);
#pragma unroll
        for (int d = 0; d < 16; ++d) acc[d] = fmaf(acc[d], alpha, w * enc_b[d]);
        m = mn;
      }
    }
    // ---- last entity k = 14 (single) ----
    {
      float2 a01 = ld2(srow + 4  + 2*14);
      float2 a23 = ld2(srow + 34 + 2*14);
      float enc[16];
#pragma unroll
      for (int d = 0; d < 16; ++d) enc[d] = W.oa_b2[d];
#pragma unroll
      for (int j = 0; j < 32; ++j) {
        float h = W.oa_b1[j];
        h = fmaf(a01.x, W.oa_W1[ 0 + j], h);
        h = fmaf(a01.y, W.oa_W1[32 + j], h);
        h = fmaf(a23.x, W.oa_W1[64 + j], h);
        h = fmaf(a23.y, W.oa_W1[96 + j], h);
        h = fmaxf(h, 0.f);
#pragma unroll
        for (int d = 0; d < 16; ++d) enc[d] = fmaf(h, W.oa_W2[j*16 + d], enc[d]);
      }
      float s = 0.f;
#pragma unroll
      for (int d = 0; d < 16; ++d) {
        enc[d] = fmaxf(enc[d], 0.f);
        s = fmaf(self_out[d], enc[d], s);
      }
      s *= 0.25f;
      float mn = fmaxf(m, s);
      float alpha = __expf(m - mn), w = __expf(s - mn);
      l = fmaf(l, alpha, w);
#pragma unroll
      for (int d = 0; d < 16; ++d) acc[d] = fmaf(acc[d], alpha, w * enc[d]);
      m = mn;
    }
    float inv = 1.f / l;
    float mu = 0.f;
#pragma unroll
    for (int d = 0; d < 16; ++d) { acc[d] *= inv; mu += acc[d]; }
    mu *= (1.f / 16.f);
    float var = 0.f;
#pragma unroll
    for (int d = 0; d < 16; ++d) { float x = acc[d] - mu; var = fmaf(x, x, var); }
    var *= (1.f / 16.f);
    float rstd = rsqrtf(var + LN_EPS);
#pragma unroll
    for (int d = 0; d < 16; ++d)
      other_pool[d] = fmaxf(fmaf((acc[d] - mu) * rstd, W.oa_g[d], W.oa_b[d]), 0.f);
  }

  // ------- food: 16 x (2->32->16), processed in pairs -------
  float food_pool[16];
  {
    float m = -3.0e38f, l = 0.f, acc[16];
#pragma unroll
    for (int d = 0; d < 16; ++d) acc[d] = 0.f;

#pragma unroll 1
    for (int kp = 0; kp < 16; kp += 2) {
      float2 fa = ld2(srow + 64 + 2*kp);
      float2 fb = ld2(srow + 64 + 2*kp + 2);
      float enc_a[16], enc_b[16];
#pragma unroll
      for (int d = 0; d < 16; ++d) { float b2 = W.go_b2[d]; enc_a[d] = b2; enc_b[d] = b2; }
#pragma unroll
      for (int j = 0; j < 32; ++j) {
        float w0 = W.go_W1[0 + j], w1 = W.go_W1[32 + j];
        float b1 = W.go_b1[j];
        float ha = fmaf(fa.x, w0, b1); ha = fmaf(fa.y, w1, ha); ha = fmaxf(ha, 0.f);
        float hb = fmaf(fb.x, w0, b1); hb = fmaf(fb.y, w1, hb); hb = fmaxf(hb, 0.f);
#pragma unroll
        for (int d = 0; d < 16; ++d) {
          float w = W.go_W2[j*16 + d];
          enc_a[d] = fmaf(ha, w, enc_a[d]);
          enc_b[d] = fmaf(hb, w, enc_b[d]);
        }
      }
      float sa = 0.f, sb = 0.f;
#pragma unroll
      for (int d = 0; d < 16; ++d) {
        enc_a[d] = fmaxf(enc_a[d], 0.f);
        enc_b[d] = fmaxf(enc_b[d], 0.f);
        sa = fmaf(self_out[d], enc_a[d], sa);
        sb = fmaf(self_out[d], enc_b[d], sb);
      }
      sa *= 0.25f; sb *= 0.25f;
      {
        float mn = fmaxf(m, sa);
        float alpha = __expf(m - mn), w = __expf(sa - mn);
        l = fmaf(l, alpha, w);
#pragma unroll
        for (int d = 0; d < 16; ++d) acc[d] = fmaf(acc[d], alpha, w * enc_a[d]);
        m = mn;
      }
      {
        float mn = fmaxf(m, sb);
        float alpha = __expf(m - mn), w = __expf(sb - mn);
        l = fmaf(l, alpha, w);
#pragma unroll
        for (int d = 0; d < 16; ++d) acc[d] = fmaf(acc[d], alpha, w * enc_b[d]);
        m = mn;
      }
    }
    float inv = 1.f / l;
    float mu = 0.f;
#pragma unroll
    for (int d = 0; d < 16; ++d) { acc[d] *= inv; mu += acc[d]; }
    mu *= (1.f / 16.f);
    float var = 0.f;
#pragma unroll
    for (int d = 0; d < 16; ++d) { float x = acc[d] - mu; var = fmaf(x, x, var); }
    var *= (1.f / 16.f);
    float rstd = rsqrtf(var + LN_EPS);
#pragma unroll
    for (int d = 0; d < 16; ++d)
      food_pool[d] = fmaxf(fmaf((acc[d] - mu) * rstd, W.go_g[d], W.go_b[d]), 0.f);
  }

  // ------- action head: 48 -> 32 -> 32 -> 2, leaky_relu(0.01), tanh -------
  // merged order: [self, food, other]
  float h1[32];
#pragma unroll
  for (int j = 0; j < 32; ++j) h1[j] = W.a_b1[j];
#pragma unroll
  for (int c = 0; c < 16; ++c) {
    float v = self_out[c];
#pragma unroll
    for (int j = 0; j < 32; ++j) h1[j] = fmaf(v, W.a_W1[c*32 + j], h1[j]);
  }
#pragma unroll
  for (int c = 0; c < 16; ++c) {
    float v = food_pool[c];
#pragma unroll
    for (int j = 0; j < 32; ++j) h1[j] = fmaf(v, W.a_W1[(16 + c)*32 + j], h1[j]);
  }
#pragma unroll
  for (int c = 0; c < 16; ++c) {
    float v = other_pool[c];
#pragma unroll
    for (int j = 0; j < 32; ++j) h1[j] = fmaf(v, W.a_W1[(32 + c)*32 + j], h1[j]);
  }
#pragma unroll
  for (int j = 0; j < 32; ++j) h1[j] = fmaxf(h1[j], 0.01f * h1[j]);   // leaky

  float h2[32];
#pragma unroll
  for (int j = 0; j < 32; ++j) h2[j] = W.a_b2[j];
#pragma unroll
  for (int c = 0; c < 32; ++c) {
    float v = h1[c];
#pragma unroll
    for (int j = 0; j < 32; ++j) h2[j] = fmaf(v, W.a_W2[c*32 + j], h2[j]);
  }
#pragma unroll
  for (int j = 0; j < 32; ++j) h2[j] = fmaxf(h2[j], 0.01f * h2[j]);

  float o0 = W.a_b3[0], o1 = W.a_b3[1];
#pragma unroll
  for (int c = 0; c < 32; ++c) {
    o0 = fmaf(h2[c], W.a_W3[c*2 + 0], o0);
    o1 = fmaf(h2[c], W.a_W3[c*2 + 1], o1);
  }
  o0 = tanhf(o0);
  o1 = tanhf(o1);

  reinterpret_cast<float2*>(out)[row] = make_float2(o0, o1);
}

extern "C" void kernel_launch(void* const* d_in, const int* in_sizes, int n_in,
                              void* d_out, int out_size, void* d_ws, size_t ws_size,
                              hipStream_t stream) {
  const float* s_input = (const float*)d_in[0];
  Weights W;
  W.en_W1 = (const float*)d_in[1];  W.en_b1 = (const float*)d_in[2];
  W.en_W2 = (const float*)d_in[3];  W.en_b2 = (const float*)d_in[4];
  W.oa_W1 = (const float*)d_in[5];  W.oa_b1 = (const float*)d_in[6];
  W.oa_W2 = (const float*)d_in[7];  W.oa_b2 = (const float*)d_in[8];
  W.go_W1 = (const float*)d_in[9];  W.go_b1 = (const float*)d_in[10];
  W.go_W2 = (const float*)d_in[11]; W.go_b2 = (const float*)d_in[12];
  W.oa_g  = (const float*)d_in[13]; W.oa_b  = (const float*)d_in[14];
  W.go_g  = (const float*)d_in[15]; W.go_b  = (const float*)d_in[16];
  W.a_W1  = (const float*)d_in[17]; W.a_b1  = (const float*)d_in[18];
  W.a_W2  = (const float*)d_in[19]; W.a_b2  = (const float*)d_in[20];
  W.a_W3  = (const float*)d_in[21]; W.a_b3  = (const float*)d_in[22];

  const int bsz = in_sizes[0] / 96;          // 262144
  const int blocks = (bsz + 255) / 256;      // 1024
  actor_fwd<<<blocks, 256, 0, stream>>>(s_input, W, (float*)d_out, bsz);
}

// Round 9
// 442.153 us; speedup vs baseline: 2.8210x; 1.0375x over previous
//
#include <hip/hip_runtime.h>

// Actor_attf_single — MI355X (gfx950)
// R9: wave-specialization TLP. Ledger: R8 = 329us, wall 790K cyc/SIMD vs
// ~207K issue demand => ~4x stall gap; s_load halving gave only 9% => stalls
// are latency waves can't hide at 4 waves/SIMD. R6 failed because it split
// rows across LANES (divergent k-bounds = all lanes run all k, half masked);
// this splits across WAVES (uniform branches, s_loads stay scalar):
//   - 2 waves per 64-row group: role 0 = self+other+head, role 1 = self+food
//   - food_pool handed over via padded LDS (+1 stride, conflict-free)
//   - grid doubles to 8192 waves = 8/SIMD resident (VGPR 64 allows it)
//   - per-wave critical path 26K -> ~15K inst; per-wave weight stream halved
//   - pool math verbatim from R8 (absmax must stay 0.00390625)

#define LN_EPS 1e-5f

struct Weights {
  const float* __restrict__ en_W1; const float* __restrict__ en_b1;
  const float* __restrict__ en_W2; const float* __restrict__ en_b2;
  const float* __restrict__ oa_W1; const float* __restrict__ oa_b1;
  const float* __restrict__ oa_W2; const float* __restrict__ oa_b2;
  const float* __restrict__ go_W1; const float* __restrict__ go_b1;
  const float* __restrict__ go_W2; const float* __restrict__ go_b2;
  const float* __restrict__ oa_g;  const float* __restrict__ oa_b;
  const float* __restrict__ go_g;  const float* __restrict__ go_b;
  const float* __restrict__ a_W1;  const float* __restrict__ a_b1;
  const float* __restrict__ a_W2;  const float* __restrict__ a_b2;
  const float* __restrict__ a_W3;  const float* __restrict__ a_b3;
};

__device__ __forceinline__ float2 ld2(const float* __restrict__ p) {
  return *reinterpret_cast<const float2*>(p);
}

__global__ __launch_bounds__(256)
void actor_fwd(const float* __restrict__ s_input, Weights W,
               float* __restrict__ out, int bsz) {
  const int lane    = threadIdx.x & 63;
  const int wv      = threadIdx.x >> 6;      // 0..3
  const int pairIdx = wv >> 1;               // 0..1  (64-row group in block)
  const int role    = wv & 1;                // 0: other+head, 1: food
  int row = blockIdx.x * 128 + pairIdx * 64 + lane;
  row = min(row, bsz - 1);
  const float* __restrict__ srow = s_input + (size_t)row * 96;

  __shared__ float fpool[2][64][17];         // +1 pad: conflict-free

  // ---------------- self encoder: fused 4 -> 32 -> 16, relu (both roles) ----
  float self_out[16];
  {
    float2 p01 = ld2(srow + 0);
    float2 p23 = ld2(srow + 2);
#pragma unroll
    for (int d = 0; d < 16; ++d) self_out[d] = W.en_b2[d];
#pragma unroll
    for (int j = 0; j < 32; ++j) {
      float h = W.en_b1[j];
      h = fmaf(p01.x, W.en_W1[ 0 + j], h);
      h = fmaf(p01.y, W.en_W1[32 + j], h);
      h = fmaf(p23.x, W.en_W1[64 + j], h);
      h = fmaf(p23.y, W.en_W1[96 + j], h);
      h = fmaxf(h, 0.f);
#pragma unroll
      for (int d = 0; d < 16; ++d) self_out[d] = fmaf(h, W.en_W2[j*16 + d], self_out[d]);
    }
#pragma unroll
    for (int d = 0; d < 16; ++d) self_out[d] = fmaxf(self_out[d], 0.f);
  }

  float other_pool[16];

  if (role == 0) {
    // ------- other agents: 15 x (4->32->16), pairs (verbatim R8) -------
    float m = -3.0e38f, l = 0.f, acc[16];
#pragma unroll
    for (int d = 0; d < 16; ++d) acc[d] = 0.f;
#pragma unroll 1
    for (int kp = 0; kp < 14; kp += 2) {
      float2 a01 = ld2(srow + 4  + 2*kp);
      float2 a23 = ld2(srow + 34 + 2*kp);
      float2 b01 = ld2(srow + 4  + 2*kp + 2);
      float2 b23 = ld2(srow + 34 + 2*kp + 2);
      float enc_a[16], enc_b[16];
#pragma unroll
      for (int d = 0; d < 16; ++d) { float b2 = W.oa_b2[d]; enc_a[d] = b2; enc_b[d] = b2; }
#pragma unroll
      for (int j = 0; j < 32; ++j) {
        float w0 = W.oa_W1[ 0 + j], w1 = W.oa_W1[32 + j];
        float w2 = W.oa_W1[64 + j], w3 = W.oa_W1[96 + j];
        float b1 = W.oa_b1[j];
        float ha = fmaf(a01.x, w0, b1); ha = fmaf(a01.y, w1, ha);
        ha = fmaf(a23.x, w2, ha);       ha = fmaf(a23.y, w3, ha);
        ha = fmaxf(ha, 0.f);
        float hb = fmaf(b01.x, w0, b1); hb = fmaf(b01.y, w1, hb);
        hb = fmaf(b23.x, w2, hb);       hb = fmaf(b23.y, w3, hb);
        hb = fmaxf(hb, 0.f);
#pragma unroll
        for (int d = 0; d < 16; ++d) {
          float w = W.oa_W2[j*16 + d];
          enc_a[d] = fmaf(ha, w, enc_a[d]);
          enc_b[d] = fmaf(hb, w, enc_b[d]);
        }
      }
      float sa = 0.f, sb = 0.f;
#pragma unroll
      for (int d = 0; d < 16; ++d) {
        enc_a[d] = fmaxf(enc_a[d], 0.f);
        enc_b[d] = fmaxf(enc_b[d], 0.f);
        sa = fmaf(self_out[d], enc_a[d], sa);
        sb = fmaf(self_out[d], enc_b[d], sb);
      }
      sa *= 0.25f; sb *= 0.25f;
      {
        float mn = fmaxf(m, sa);
        float alpha = __expf(m - mn), w = __expf(sa - mn);
        l = fmaf(l, alpha, w);
#pragma unroll
        for (int d = 0; d < 16; ++d) acc[d] = fmaf(acc[d], alpha, w * enc_a[d]);
        m = mn;
      }
      {
        float mn = fmaxf(m, sb);
        float alpha = __expf(m - mn), w = __expf(sb - mn);
        l = fmaf(l, alpha, w);
#pragma unroll
        for (int d = 0; d < 16; ++d) acc[d] = fmaf(acc[d], alpha, w * enc_b[d]);
        m = mn;
      }
    }
    { // last entity k = 14
      float2 a01 = ld2(srow + 4  + 2*14);
      float2 a23 = ld2(srow + 34 + 2*14);
      float enc[16];
#pragma unroll
      for (int d = 0; d < 16; ++d) enc[d] = W.oa_b2[d];
#pragma unroll
      for (int j = 0; j < 32; ++j) {
        float h = W.oa_b1[j];
        h = fmaf(a01.x, W.oa_W1[ 0 + j], h);
        h = fmaf(a01.y, W.oa_W1[32 + j], h);
        h = fmaf(a23.x, W.oa_W1[64 + j], h);
        h = fmaf(a23.y, W.oa_W1[96 + j], h);
        h = fmaxf(h, 0.f);
#pragma unroll
        for (int d = 0; d < 16; ++d) enc[d] = fmaf(h, W.oa_W2[j*16 + d], enc[d]);
      }
      float s = 0.f;
#pragma unroll
      for (int d = 0; d < 16; ++d) {
        enc[d] = fmaxf(enc[d], 0.f);
        s = fmaf(self_out[d], enc[d], s);
      }
      s *= 0.25f;
      float mn = fmaxf(m, s);
      float alpha = __expf(m - mn), w = __expf(s - mn);
      l = fmaf(l, alpha, w);
#pragma unroll
      for (int d = 0; d < 16; ++d) acc[d] = fmaf(acc[d], alpha, w * enc[d]);
      m = mn;
    }
    float inv = 1.f / l;
    float mu = 0.f;
#pragma unroll
    for (int d = 0; d < 16; ++d) { acc[d] *= inv; mu += acc[d]; }
    mu *= (1.f / 16.f);
    float var = 0.f;
#pragma unroll
    for (int d = 0; d < 16; ++d) { float x = acc[d] - mu; var = fmaf(x, x, var); }
    var *= (1.f / 16.f);
    float rstd = rsqrtf(var + LN_EPS);
#pragma unroll
    for (int d = 0; d < 16; ++d)
      other_pool[d] = fmaxf(fmaf((acc[d] - mu) * rstd, W.oa_g[d], W.oa_b[d]), 0.f);
  } else {
    // ------- food: 16 x (2->32->16), pairs (verbatim R8) -> LDS -------
    float m = -3.0e38f, l = 0.f, acc[16];
#pragma unroll
    for (int d = 0; d < 16; ++d) acc[d] = 0.f;
#pragma unroll 1
    for (int kp = 0; kp < 16; kp += 2) {
      float2 fa = ld2(srow + 64 + 2*kp);
      float2 fb = ld2(srow + 64 + 2*kp + 2);
      float enc_a[16], enc_b[16];
#pragma unroll
      for (int d = 0; d < 16; ++d) { float b2 = W.go_b2[d]; enc_a[d] = b2; enc_b[d] = b2; }
#pragma unroll
      for (int j = 0; j < 32; ++j) {
        float w0 = W.go_W1[0 + j], w1 = W.go_W1[32 + j];
        float b1 = W.go_b1[j];
        float ha = fmaf(fa.x, w0, b1); ha = fmaf(fa.y, w1, ha); ha = fmaxf(ha, 0.f);
        float hb = fmaf(fb.x, w0, b1); hb = fmaf(fb.y, w1, hb); hb = fmaxf(hb, 0.f);
#pragma unroll
        for (int d = 0; d < 16; ++d) {
          float w = W.go_W2[j*16 + d];
          enc_a[d] = fmaf(ha, w, enc_a[d]);
          enc_b[d] = fmaf(hb, w, enc_b[d]);
        }
      }
      float sa = 0.f, sb = 0.f;
#pragma unroll
      for (int d = 0; d < 16; ++d) {
        enc_a[d] = fmaxf(enc_a[d], 0.f);
        enc_b[d] = fmaxf(enc_b[d], 0.f);
        sa = fmaf(self_out[d], enc_a[d], sa);
        sb = fmaf(self_out[d], enc_b[d], sb);
      }
      sa *= 0.25f; sb *= 0.25f;
      {
        float mn = fmaxf(m, sa);
        float alpha = __expf(m - mn), w = __expf(sa - mn);
        l = fmaf(l, alpha, w);
#pragma unroll
        for (int d = 0; d < 16; ++d) acc[d] = fmaf(acc[d], alpha, w * enc_a[d]);
        m = mn;
      }
      {
        float mn = fmaxf(m, sb);
        float alpha = __expf(m - mn), w = __expf(sb - mn);
        l = fmaf(l, alpha, w);
#pragma unroll
        for (int d = 0; d < 16; ++d) acc[d] = fmaf(acc[d], alpha, w * enc_b[d]);
        m = mn;
      }
    }
    float inv = 1.f / l;
    float mu = 0.f;
#pragma unroll
    for (int d = 0; d < 16; ++d) { acc[d] *= inv; mu += acc[d]; }
    mu *= (1.f / 16.f);
    float var = 0.f;
#pragma unroll
    for (int d = 0; d < 16; ++d) { float x = acc[d] - mu; var = fmaf(x, x, var); }
    var *= (1.f / 16.f);
    float rstd = rsqrtf(var + LN_EPS);
#pragma unroll
    for (int d = 0; d < 16; ++d) {
      float fp = fmaxf(fmaf((acc[d] - mu) * rstd, W.go_g[d], W.go_b[d]), 0.f);
      fpool[pairIdx][lane][d] = fp;
    }
  }

  __syncthreads();
  if (role != 0) return;

  // ------- action head (role 0): 48 -> 32 -> 32 -> 2 -------
  float food_pool[16];
#pragma unroll
  for (int d = 0; d < 16; ++d) food_pool[d] = fpool[pairIdx][lane][d];

  float h1[32];
#pragma unroll
  for (int j = 0; j < 32; ++j) h1[j] = W.a_b1[j];
#pragma unroll
  for (int c = 0; c < 16; ++c) {
    float v = self_out[c];
#pragma unroll
    for (int j = 0; j < 32; ++j) h1[j] = fmaf(v, W.a_W1[c*32 + j], h1[j]);
  }
#pragma unroll
  for (int c = 0; c < 16; ++c) {
    float v = food_pool[c];
#pragma unroll
    for (int j = 0; j < 32; ++j) h1[j] = fmaf(v, W.a_W1[(16 + c)*32 + j], h1[j]);
  }
#pragma unroll
  for (int c = 0; c < 16; ++c) {
    float v = other_pool[c];
#pragma unroll
    for (int j = 0; j < 32; ++j) h1[j] = fmaf(v, W.a_W1[(32 + c)*32 + j], h1[j]);
  }
#pragma unroll
  for (int j = 0; j < 32; ++j) h1[j] = fmaxf(h1[j], 0.01f * h1[j]);   // leaky

  float h2[32];
#pragma unroll
  for (int j = 0; j < 32; ++j) h2[j] = W.a_b2[j];
#pragma unroll
  for (int c = 0; c < 32; ++c) {
    float v = h1[c];
#pragma unroll
    for (int j = 0; j < 32; ++j) h2[j] = fmaf(v, W.a_W2[c*32 + j], h2[j]);
  }
#pragma unroll
  for (int j = 0; j < 32; ++j) h2[j] = fmaxf(h2[j], 0.01f * h2[j]);

  float o0 = W.a_b3[0], o1 = W.a_b3[1];
#pragma unroll
  for (int c = 0; c < 32; ++c) {
    o0 = fmaf(h2[c], W.a_W3[c*2 + 0], o0);
    o1 = fmaf(h2[c], W.a_W3[c*2 + 1], o1);
  }
  o0 = tanhf(o0);
  o1 = tanhf(o1);

  reinterpret_cast<float2*>(out)[row] = make_float2(o0, o1);
}

extern "C" void kernel_launch(void* const* d_in, const int* in_sizes, int n_in,
                              void* d_out, int out_size, void* d_ws, size_t ws_size,
                              hipStream_t stream) {
  const float* s_input = (const float*)d_in[0];
  Weights W;
  W.en_W1 = (const float*)d_in[1];  W.en_b1 = (const float*)d_in[2];
  W.en_W2 = (const float*)d_in[3];  W.en_b2 = (const float*)d_in[4];
  W.oa_W1 = (const float*)d_in[5];  W.oa_b1 = (const float*)d_in[6];
  W.oa_W2 = (const float*)d_in[7];  W.oa_b2 = (const float*)d_in[8];
  W.go_W1 = (const float*)d_in[9];  W.go_b1 = (const float*)d_in[10];
  W.go_W2 = (const float*)d_in[11]; W.go_b2 = (const float*)d_in[12];
  W.oa_g  = (const float*)d_in[13]; W.oa_b  = (const float*)d_in[14];
  W.go_g  = (const float*)d_in[15]; W.go_b  = (const float*)d_in[16];
  W.a_W1  = (const float*)d_in[17]; W.a_b1  = (const float*)d_in[18];
  W.a_W2  = (const float*)d_in[19]; W.a_b2  = (const float*)d_in[20];
  W.a_W3  = (const float*)d_in[21]; W.a_b3  = (const float*)d_in[22];

  const int bsz = in_sizes[0] / 96;          // 262144
  const int blocks = (bsz + 127) / 128;      // 128 rows per block (2 groups x 2 waves)
  actor_fwd<<<blocks, 256, 0, stream>>>(s_input, W, (float*)d_out, bsz);
}